// Round 3
// baseline (194.247 us; speedup 1.0000x reference)
//
#include <hip/hip_runtime.h>

// SoftErosion3D, connectivity=6, iterations=2, shape [2,1,256,256,256] f32.
// FUSED both iterations in one kernel: block owns a 16x64 (H,W) tile and
// marches along D keeping 3 rolling iter-1 planes in LDS.
//   iter1(x) = x^2 * prod(6 face neighbors), pad 1.0
//   out = iter1(iter1(im))
// HBM: read input once (~134MB, LLC-cached halos), NT-write output once.

#define DD 256
#define HH 256
#define WW 256
#define HW (HH * WW)

#define WT 64          // W tile (16 float4)
#define HT 16          // H tile
#define DT 32          // D march per block
#define LROWS (HT + 2) // 18
#define LSTRIDE 72     // floats per LDS row: [0..2] pad, 3 = left halo,
                       // 4..67 main, 68 = right halo; mult of 4 -> f4 aligned

typedef float nfloat4 __attribute__((ext_vector_type(4)));  // native vec for NT store

// iter-1 value for a float4 at (d, h, w..w+3). d must be in [0,256); h may be
// out of range (-> pad 1.0). w is 16B-aligned and in range.
__device__ __forceinline__ float4 iter1_f4(const float* __restrict__ ip,
                                           int d, int h, int w) {
    float4 r = {1.f, 1.f, 1.f, 1.f};
    if ((unsigned)h >= (unsigned)HH) return r;
    const float* p = ip + ((d << 16) | (h << 8) | w);
    float4 c = *reinterpret_cast<const float4*>(p);
    r.x = c.x * c.x; r.y = c.y * c.y; r.z = c.z * c.z; r.w = c.w * c.w;
    float lw = (w > 0)      ? p[-1] : 1.f;
    float rw = (w < WW - 4) ? p[4]  : 1.f;
    r.x *= lw  * c.y;
    r.y *= c.x * c.z;
    r.z *= c.y * c.w;
    r.w *= c.z * rw;
    if (h > 0)      { float4 n = *reinterpret_cast<const float4*>(p - WW); r.x*=n.x; r.y*=n.y; r.z*=n.z; r.w*=n.w; }
    if (h < HH - 1) { float4 n = *reinterpret_cast<const float4*>(p + WW); r.x*=n.x; r.y*=n.y; r.z*=n.z; r.w*=n.w; }
    if (d > 0)      { float4 n = *reinterpret_cast<const float4*>(p - HW); r.x*=n.x; r.y*=n.y; r.z*=n.z; r.w*=n.w; }
    if (d < DD - 1) { float4 n = *reinterpret_cast<const float4*>(p + HW); r.x*=n.x; r.y*=n.y; r.z*=n.z; r.w*=n.w; }
    return r;
}

// scalar iter-1 for halo columns; h and w may be out of range (-> 1.0)
__device__ __forceinline__ float iter1_s(const float* __restrict__ ip,
                                         int d, int h, int w) {
    if ((unsigned)h >= (unsigned)HH || (unsigned)w >= (unsigned)WW) return 1.f;
    const float* p = ip + ((d << 16) | (h << 8) | w);
    float c = *p;
    float r = c * c;
    if (w > 0)      r *= p[-1];
    if (w < WW - 1) r *= p[1];
    if (h > 0)      r *= p[-WW];
    if (h < HH - 1) r *= p[WW];
    if (d > 0)      r *= p[-HW];
    if (d < DD - 1) r *= p[HW];
    return r;
}

__global__ __launch_bounds__(256) void erode6_fused(const float* __restrict__ in,
                                                    float* __restrict__ out) {
    const int bx = blockIdx.x;
    const int w0 = (bx & 3) * WT;
    const int h0 = ((bx >> 2) & 15) * HT;
    const int d0 = ((bx >> 6) & 7) * DT;
    const int b  = bx >> 9;
    const float* __restrict__ ip = in  + (size_t)b * (DD * HW);
    float* __restrict__       op = out + (size_t)b * (DD * HW);

    __shared__ float s1[3][LROWS][LSTRIDE];

    const int tid = threadIdx.x;
    const int hr  = tid >> 4;   // 0..15
    const int cc  = tid & 15;   // 0..15 (float4 column)

    // compute iter-1 plane p into LDS slot (p+3)%3; out-of-volume plane -> 1.0
    auto compute_plane = [&](int p) {
        float (*sl)[LSTRIDE] = s1[(p + 3) % 3];
        if ((unsigned)p >= (unsigned)DD) {
            for (int i = tid; i < LROWS * LSTRIDE; i += 256)
                (&sl[0][0])[i] = 1.f;
            return;
        }
        {   // rows 0..15 of the 18-row halo plane
            int lr = hr;
            float4 v = iter1_f4(ip, p, h0 - 1 + lr, w0 + 4 * cc);
            *reinterpret_cast<float4*>(&sl[lr][4 + 4 * cc]) = v;
        }
        if (tid < 32) {  // rows 16,17
            int lr = 16 + (tid >> 4);
            int c2 = tid & 15;
            float4 v = iter1_f4(ip, p, h0 - 1 + lr, w0 + 4 * c2);
            *reinterpret_cast<float4*>(&sl[lr][4 + 4 * c2]) = v;
        }
        if (tid < 2 * LROWS) {  // halo columns w0-1 and w0+WT, all 18 rows
            int lr = tid >> 1;
            int right = tid & 1;
            int w = right ? (w0 + WT) : (w0 - 1);
            sl[lr][right ? 68 : 3] = iter1_s(ip, p, h0 - 1 + lr, w);
        }
    };

    // prologue: planes d0-1 and d0 (different slots, one sync suffices)
    compute_plane(d0 - 1);
    compute_plane(d0);

    for (int d = d0; d < d0 + DT; ++d) {
        compute_plane(d + 1);
        __syncthreads();

        // iter-2 at plane d from LDS slots d-1, d, d+1
        float (*sm)[LSTRIDE] = s1[d % 3];
        float (*sf)[LSTRIDE] = s1[(d + 2) % 3];  // plane d-1
        float (*sb)[LSTRIDE] = s1[(d + 1) % 3];  // plane d+1
        const int lr  = hr + 1;        // 1..16
        const int col = 4 + 4 * cc;    // 4..64

        float4 c = *reinterpret_cast<const float4*>(&sm[lr][col]);
        float4 r;
        r.x = c.x * c.x; r.y = c.y * c.y; r.z = c.z * c.z; r.w = c.w * c.w;
        float lw = sm[lr][col - 1];
        float rw = sm[lr][col + 4];
        r.x *= lw  * c.y;
        r.y *= c.x * c.z;
        r.z *= c.y * c.w;
        r.w *= c.z * rw;
        float4 n;
        n = *reinterpret_cast<const float4*>(&sm[lr - 1][col]); r.x*=n.x; r.y*=n.y; r.z*=n.z; r.w*=n.w;
        n = *reinterpret_cast<const float4*>(&sm[lr + 1][col]); r.x*=n.x; r.y*=n.y; r.z*=n.z; r.w*=n.w;
        n = *reinterpret_cast<const float4*>(&sf[lr][col]);     r.x*=n.x; r.y*=n.y; r.z*=n.z; r.w*=n.w;
        n = *reinterpret_cast<const float4*>(&sb[lr][col]);     r.x*=n.x; r.y*=n.y; r.z*=n.z; r.w*=n.w;

        nfloat4* dst = reinterpret_cast<nfloat4*>(
            op + ((d << 16) | ((h0 + hr) << 8) | (w0 + 4 * cc)));
        nfloat4 rv = {r.x, r.y, r.z, r.w};
        __builtin_nontemporal_store(rv, dst);

        __syncthreads();  // before next compute_plane overwrites slot (d-1)%3
    }
}

extern "C" void kernel_launch(void* const* d_in, const int* in_sizes, int n_in,
                              void* d_out, int out_size, void* d_ws, size_t ws_size,
                              hipStream_t stream) {
    const float* in  = (const float*)d_in[0];
    float*       out = (float*)d_out;

    // grid: 4 (W) * 16 (H) * 8 (D chunks) * 2 (batch) = 1024 blocks
    dim3 block(256);
    dim3 grid(1024);
    erode6_fused<<<grid, block, 0, stream>>>(in, out);
}

// Round 4
// 74.556 us; speedup vs baseline: 2.6054x; 2.6054x over previous
//
#include <hip/hip_runtime.h>

// SoftErosion3D, connectivity=6, iterations=2, [2,1,256,256,256] f32.
//   iter1(x) = x^2 * prod(6 face neighbors), pad 1.0 ; out = iter1(iter1(im))
// Fused, NO LDS, NO barriers. Wave = one full W row (64 lanes x float4), so
// all w+-1 neighbors come from intra-wave shuffles. Threads march along D with
// rolling registers; 5 fresh float4 loads per output float4 (4 are L1 hits).

#define DD 256
#define HH 256
#define WW 256
#define HW 65536
#define DT 32

typedef float nfloat4 __attribute__((ext_vector_type(4)));

__device__ __forceinline__ float wleft(float x) {     // lane-1's x ; lane0 -> 1.0
    float v = __shfl_up(x, 1, 64);
    return ((threadIdx.x & 63) == 0) ? 1.0f : v;
}
__device__ __forceinline__ float wright(float x) {    // lane+1's x ; lane63 -> 1.0
    float v = __shfl_down(x, 1, 64);
    return ((threadIdx.x & 63) == 63) ? 1.0f : v;
}
__device__ __forceinline__ float4 f4mul(float4 a, float4 b) {
    a.x *= b.x; a.y *= b.y; a.z *= b.z; a.w *= b.w; return a;
}
__device__ __forceinline__ float4 sel1(float4 v, bool p) {  // p ? v : 1.0
    float4 o = {1.f, 1.f, 1.f, 1.f};
    return p ? v : o;  // branchless cndmask (p is wave-uniform anyway)
}

// iter1 at one float4 from registers. c = center f4; pm/pp = plane d-1/d+1
// same row; hm/hp = row h-1/h+1 same plane. Invalid neighbors -> skip (x1.0).
// w+-1 neighbors via shuffles of c.
__device__ __forceinline__ float4 iter1r(float4 c,
                                         float4 pm, bool vpm,
                                         float4 pp, bool vpp,
                                         float4 hm, bool vhm,
                                         float4 hp, bool vhp) {
    float lw = wleft(c.w), rw = wright(c.x);
    float4 r;
    r.x = c.x * c.x * (lw  * c.y);
    r.y = c.y * c.y * (c.x * c.z);
    r.z = c.z * c.z * (c.y * c.w);
    r.w = c.w * c.w * (c.z * rw);
    r = f4mul(r, sel1(pm, vpm));
    r = f4mul(r, sel1(pp, vpp));
    r = f4mul(r, sel1(hm, vhm));
    r = f4mul(r, sel1(hp, vhp));
    return r;
}

__device__ __forceinline__ int dcl(int d) { return d < 0 ? 0 : (d > DD - 1 ? DD - 1 : d); }

__global__ __launch_bounds__(256) void erode6_fused(const float* __restrict__ in,
                                                    float* __restrict__ out) {
    const int bx = blockIdx.x;
    const int cc = threadIdx.x & 63;          // f4 column, w = cc*4
    const int hr = threadIdx.x >> 6;          // 0..3
    const int h  = ((bx & 63) << 2) + hr;     // wave-uniform
    const int d0 = ((bx >> 6) & 7) * DT;
    const int b  = bx >> 9;

    const float* __restrict__ ip = in  + (size_t)b * (DD * HW);
    float* __restrict__       op = out + (size_t)b * (DD * HW);

    const bool vU  = (h >= 1), vUU = (h >= 2);
    const bool vD  = (h <= HH - 2), vDD = (h <= HH - 3);
    const int hU  = vU  ? h - 1 : 0;
    const int hUU = vUU ? h - 2 : 0;
    const int hD  = vD  ? h + 1 : HH - 1;
    const int hDD = vDD ? h + 2 : HH - 1;

    const float* pC  = ip + (h   << 8) + (cc << 2);
    const float* pU  = ip + (hU  << 8) + (cc << 2);
    const float* pUU = ip + (hUU << 8) + (cc << 2);
    const float* pD  = ip + (hD  << 8) + (cc << 2);
    const float* pDD = ip + (hDD << 8) + (cc << 2);

#define LD(base, dpl) (*reinterpret_cast<const float4*>((base) + ((dpl) << 16)))

    // ---- prologue: state for first output plane t = d0 ----
    float4 cm2  = LD(pC, dcl(d0 - 2));
    float4 cm1  = LD(pC, dcl(d0 - 1));
    float4 inC0 = LD(pC, d0);            // in(t,   h)
    float4 inC1 = LD(pC, d0 + 1);        // in(t+1, h)   (d0+1 <= 225, in range)
    float4 inU0 = LD(pU, dcl(d0 - 1));   // in(t-1, h-1)
    float4 inU1 = LD(pU, d0);            // in(t,   h-1)
    float4 inD0 = LD(pD, dcl(d0 - 1));   // in(t-1, h+1)
    float4 inD1 = LD(pD, d0);            // in(t,   h+1)

    // A = iter1(d0-1, h) (garbage if d0==0, unused then); B = iter1(d0, h)
    float4 A = iter1r(cm1, cm2, d0 >= 2, inC0, true, inU0, vU, inD0, vD);
    float4 B = iter1r(inC0, cm1, d0 >= 1, inC1, true, inU1, vU, inD1, vD);

    for (int t = d0; t < d0 + DT; ++t) {
        // ---- fresh loads (5 f4); addresses independent of compute below ----
        float4 c2  = LD(pC,  dcl(t + 2));  // in(t+2, h)
        float4 u1  = LD(pU,  dcl(t + 1));  // in(t+1, h-1)
        float4 d1  = LD(pD,  dcl(t + 1));  // in(t+1, h+1)
        float4 uu0 = LD(pUU, t);           // in(t,   h-2)
        float4 dd0 = LD(pDD, t);           // in(t,   h+2)

        // iter1(t+1, h)
        float4 Cn = iter1r(inC1, inC0, true, c2, t + 1 < DD - 1 || t + 2 <= DD - 1,
                           u1, vU, d1, vD);
        // note: pp (=in(t+2)) valid iff t+2 <= 255
        // (expression above: t+2 <= 255)
        // iter1(t, h-1): plane nbrs in(t-1,h-1)=inU0, in(t+1,h-1)=u1;
        //                row nbrs  in(t,h-2)=uu0,     in(t,h)=inC0
        float4 Un = sel1(iter1r(inU1, inU0, t > 0, u1, t < DD - 1, uu0, vUU, inC0, true), vU);
        // iter1(t, h+1)
        float4 Dn = sel1(iter1r(inD1, inD0, t > 0, d1, t < DD - 1, inC0, true, dd0, vDD), vD);

        // ---- iter2(t, h, w) ----
        float lw = wleft(B.w), rw = wright(B.x);
        float4 o;
        o.x = B.x * B.x * (lw  * B.y);
        o.y = B.y * B.y * (B.x * B.z);
        o.z = B.z * B.z * (B.y * B.w);
        o.w = B.w * B.w * (B.z * rw);
        o = f4mul(o, sel1(A,  t > 0));
        o = f4mul(o, sel1(Cn, t < DD - 1));
        o = f4mul(o, Un);
        o = f4mul(o, Dn);

        nfloat4 ov = {o.x, o.y, o.z, o.w};
        __builtin_nontemporal_store(ov,
            reinterpret_cast<nfloat4*>(op + (t << 16) + (h << 8) + (cc << 2)));

        // ---- roll ----
        A = B; B = Cn;
        inC0 = inC1; inC1 = c2;
        inU0 = inU1; inU1 = u1;
        inD0 = inD1; inD1 = d1;
    }
#undef LD
}

extern "C" void kernel_launch(void* const* d_in, const int* in_sizes, int n_in,
                              void* d_out, int out_size, void* d_ws, size_t ws_size,
                              hipStream_t stream) {
    const float* in  = (const float*)d_in[0];
    float*       out = (float*)d_out;

    // grid: 64 (H blocks of 4 rows) * 8 (D chunks of 32) * 2 (batch) = 1024
    dim3 block(256);
    dim3 grid(1024);
    erode6_fused<<<grid, block, 0, stream>>>(in, out);
}

// Round 5
// 59.351 us; speedup vs baseline: 3.2728x; 1.2562x over previous
//
#include <hip/hip_runtime.h>

// SoftErosion3D, connectivity=6, iterations=2, [2,1,256,256,256] f32.
//   iter1(x) = x^2 * prod(6 face neighbors), pad 1.0 ; out = iter1(iter1(im))
// Fused, NO LDS, NO barriers. Wave = one full W row (64 lanes x float4):
// w+-1 neighbors via intra-wave shuffles. Threads march along D with rolling
// registers. R4: DT=16 (2048 blocks, 8/CU), 1-deep load prefetch, XCD swizzle.

#define DD 256
#define HH 256
#define WW 256
#define HW 65536
#define DT 16

typedef float nfloat4 __attribute__((ext_vector_type(4)));

__device__ __forceinline__ float wleft(float x) {     // lane-1's x ; lane0 -> 1.0
    float v = __shfl_up(x, 1, 64);
    return ((threadIdx.x & 63) == 0) ? 1.0f : v;
}
__device__ __forceinline__ float wright(float x) {    // lane+1's x ; lane63 -> 1.0
    float v = __shfl_down(x, 1, 64);
    return ((threadIdx.x & 63) == 63) ? 1.0f : v;
}
__device__ __forceinline__ float4 f4mul(float4 a, float4 b) {
    a.x *= b.x; a.y *= b.y; a.z *= b.z; a.w *= b.w; return a;
}
__device__ __forceinline__ float4 sel1(float4 v, bool p) {  // p ? v : 1.0
    float4 o = {1.f, 1.f, 1.f, 1.f};
    return p ? v : o;  // wave-uniform p -> s_cselect
}

// iter1 at one float4 from registers. c = center f4; pm/pp = plane d-1/d+1
// same row; hm/hp = row h-1/h+1 same plane. Invalid neighbors -> x1.0.
__device__ __forceinline__ float4 iter1r(float4 c,
                                         float4 pm, bool vpm,
                                         float4 pp, bool vpp,
                                         float4 hm, bool vhm,
                                         float4 hp, bool vhp) {
    float lw = wleft(c.w), rw = wright(c.x);
    float4 r;
    r.x = c.x * c.x * (lw  * c.y);
    r.y = c.y * c.y * (c.x * c.z);
    r.z = c.z * c.z * (c.y * c.w);
    r.w = c.w * c.w * (c.z * rw);
    r = f4mul(r, sel1(pm, vpm));
    r = f4mul(r, sel1(pp, vpp));
    r = f4mul(r, sel1(hm, vhm));
    r = f4mul(r, sel1(hp, vhp));
    return r;
}

__device__ __forceinline__ int dcl(int d) { return d < 0 ? 0 : (d > DD - 1 ? DD - 1 : d); }

__global__ __launch_bounds__(256) void erode6_fused(const float* __restrict__ in,
                                                    float* __restrict__ out) {
    // XCD-chunked swizzle: 2048 blocks, 2048%8==0 -> bijective. Each XCD gets
    // a contiguous range of original ids => neighbor-H blocks share an L2.
    const int bx  = blockIdx.x;
    const int swz = (bx & 7) * 256 + (bx >> 3);

    const int cc = threadIdx.x & 63;          // f4 column, w = cc*4
    const int hr = threadIdx.x >> 6;          // 0..3
    const int h  = ((swz & 63) << 2) + hr;    // wave-uniform row
    const int d0 = ((swz >> 6) & 15) * DT;
    const int b  = swz >> 10;

    const float* __restrict__ ip = in  + (size_t)b * (DD * HW);
    float* __restrict__       op = out + (size_t)b * (DD * HW);

    const bool vU  = (h >= 1), vUU = (h >= 2);
    const bool vD  = (h <= HH - 2), vDD = (h <= HH - 3);
    const int hU  = vU  ? h - 1 : 0;
    const int hUU = vUU ? h - 2 : 0;
    const int hD  = vD  ? h + 1 : HH - 1;
    const int hDD = vDD ? h + 2 : HH - 1;

    const float* pC  = ip + (h   << 8) + (cc << 2);
    const float* pU  = ip + (hU  << 8) + (cc << 2);
    const float* pUU = ip + (hUU << 8) + (cc << 2);
    const float* pD  = ip + (hD  << 8) + (cc << 2);
    const float* pDD = ip + (hDD << 8) + (cc << 2);

#define LD(base, dpl) (*reinterpret_cast<const float4*>((base) + ((dpl) << 16)))

    // ---- prologue: rolling state for first output plane t = d0 ----
    float4 cm2  = LD(pC, dcl(d0 - 2));
    float4 cm1  = LD(pC, dcl(d0 - 1));
    float4 inC0 = LD(pC, d0);            // in(t,   h)
    float4 inC1 = LD(pC, d0 + 1);        // in(t+1, h)  (d0+1 <= 241)
    float4 inU0 = LD(pU, dcl(d0 - 1));   // in(t-1, h-1)
    float4 inU1 = LD(pU, d0);            // in(t,   h-1)
    float4 inD0 = LD(pD, dcl(d0 - 1));   // in(t-1, h+1)
    float4 inD1 = LD(pD, d0);            // in(t,   h+1)

    // A = iter1(d0-1, h) (unused if d0==0); B = iter1(d0, h)
    float4 A = iter1r(cm1, cm2, d0 >= 2, inC0, true, inU0, vU, inD0, vD);
    float4 B = iter1r(inC0, cm1, d0 >= 1, inC1, true, inU1, vU, inD1, vD);

    // ---- prefetch loads for first iteration ----
    float4 c2  = LD(pC,  dcl(d0 + 2));  // in(t+2, h)
    float4 u1  = LD(pU,  dcl(d0 + 1));  // in(t+1, h-1)
    float4 d1  = LD(pD,  dcl(d0 + 1));  // in(t+1, h+1)
    float4 uu0 = LD(pUU, d0);           // in(t,   h-2)
    float4 dd0 = LD(pDD, d0);           // in(t,   h+2)

    for (int t = d0; t < d0 + DT; ++t) {
        // ---- issue NEXT iteration's loads (hide latency under compute) ----
        float4 n_c2  = LD(pC,  dcl(t + 3));
        float4 n_u1  = LD(pU,  dcl(t + 2));
        float4 n_d1  = LD(pD,  dcl(t + 2));
        float4 n_uu0 = LD(pUU, dcl(t + 1));
        float4 n_dd0 = LD(pDD, dcl(t + 1));

        // iter1(t+1, h): pp = in(t+2) valid iff t <= 253
        float4 Cn = iter1r(inC1, inC0, true, c2, t < DD - 2, u1, vU, d1, vD);
        // iter1(t, h-1): plane nbrs inU0/u1; row nbrs uu0 / inC0
        float4 Un = sel1(iter1r(inU1, inU0, t > 0, u1, t < DD - 1, uu0, vUU, inC0, true), vU);
        // iter1(t, h+1)
        float4 Dn = sel1(iter1r(inD1, inD0, t > 0, d1, t < DD - 1, inC0, true, dd0, vDD), vD);

        // ---- iter2(t, h, w) ----
        float lw = wleft(B.w), rw = wright(B.x);
        float4 o;
        o.x = B.x * B.x * (lw  * B.y);
        o.y = B.y * B.y * (B.x * B.z);
        o.z = B.z * B.z * (B.y * B.w);
        o.w = B.w * B.w * (B.z * rw);
        o = f4mul(o, sel1(A,  t > 0));
        o = f4mul(o, sel1(Cn, t < DD - 1));
        o = f4mul(o, Un);
        o = f4mul(o, Dn);

        nfloat4 ov = {o.x, o.y, o.z, o.w};
        __builtin_nontemporal_store(ov,
            reinterpret_cast<nfloat4*>(op + (t << 16) + (h << 8) + (cc << 2)));

        // ---- roll ----
        A = B; B = Cn;
        inC0 = inC1; inC1 = c2;
        inU0 = inU1; inU1 = u1;
        inD0 = inD1; inD1 = d1;
        c2 = n_c2; u1 = n_u1; d1 = n_d1; uu0 = n_uu0; dd0 = n_dd0;
    }
#undef LD
}

extern "C" void kernel_launch(void* const* d_in, const int* in_sizes, int n_in,
                              void* d_out, int out_size, void* d_ws, size_t ws_size,
                              hipStream_t stream) {
    const float* in  = (const float*)d_in[0];
    float*       out = (float*)d_out;

    // grid: 64 (H blocks of 4 rows) * 16 (D chunks of 16) * 2 (batch) = 2048
    dim3 block(256);
    dim3 grid(2048);
    erode6_fused<<<grid, block, 0, stream>>>(in, out);
}

// Round 6
// 47.204 us; speedup vs baseline: 4.1150x; 1.2573x over previous
//
#include <hip/hip_runtime.h>

// SoftErosion3D, connectivity=6, iterations=2, [2,1,256,256,256] f32.
//   iter1(x) = x^2 * prod(6 face nbrs), pad 1.0 ; out = iter1(iter1(im))
// Fused, no LDS, no barriers. Wave = full W row (64 lanes x float4); w+-1 via
// intra-wave shuffles. R5: each thread owns TWO H rows (h, h+1) so the H-nbr
// iter1 values are in-register; boundary predicates forced to SGPR so all
// conditional factors are scalar branches, not cndmask chains.

#define DD 256
#define HH 256
#define HW 65536
#define DT 8

typedef float nfloat4 __attribute__((ext_vector_type(4)));

__device__ __forceinline__ float wleft(float x) {     // lane-1's x ; lane0 -> 1.0
    float v = __shfl_up(x, 1, 64);
    return ((threadIdx.x & 63) == 0) ? 1.0f : v;
}
__device__ __forceinline__ float wright(float x) {    // lane+1's x ; lane63 -> 1.0
    float v = __shfl_down(x, 1, 64);
    return ((threadIdx.x & 63) == 63) ? 1.0f : v;
}
__device__ __forceinline__ float4 f4mul(float4 a, float4 b) {
    a.x *= b.x; a.y *= b.y; a.z *= b.z; a.w *= b.w; return a;
}
// center^2 * in-wave W-neighbors
__device__ __forceinline__ float4 i1core(float4 c) {
    float lw = wleft(c.w), rw = wright(c.x);
    float4 r;
    r.x = c.x * c.x * (lw  * c.y);
    r.y = c.y * c.y * (c.x * c.z);
    r.z = c.z * c.z * (c.y * c.w);
    r.w = c.w * c.w * (c.z * rw);
    return r;
}

__global__ __launch_bounds__(256) void erode6_fused(const float* __restrict__ in,
                                                    float* __restrict__ out) {
    const int bx  = blockIdx.x;
    const int swz = (bx & 7) * 256 + (bx >> 3);   // 2048 blocks, bijective XCD chunking

    const int cc = threadIdx.x & 63;              // f4 column, w = cc*4
    // readfirstlane pins the wave index to SGPR -> h and all flags are scalar
    const int wv = __builtin_amdgcn_readfirstlane((int)(threadIdx.x >> 6));

    const int hblk = swz & 31;          // 32 H-blocks of 8 rows
    const int dchk = (swz >> 5) & 31;   // 32 D-chunks of 8 planes
    const int b    = swz >> 10;         // batch

    const int h = hblk * 8 + wv * 2;    // own rows h, h+1
    const int S = dchk * DT;

    const bool vbU = (h >= 1);
    const bool voU = (h >= 2);
    const bool vbD = (h + 2 <= HH - 1);
    const bool voD = (h + 3 <= HH - 1);
    const int rowU  = vbU ? h - 1 : 0;
    const int rowOU = voU ? h - 2 : 0;
    const int rowD  = vbD ? h + 2 : HH - 1;
    const int rowOD = voD ? h + 3 : HH - 1;

    const float* __restrict__ ip = in  + (size_t)b * (DD * HW);
    float* __restrict__       op = out + (size_t)b * (DD * HW);

    const float* pC0 = ip + (h     << 8) + (cc << 2);
    const float* pC1 = ip + ((h+1) << 8) + (cc << 2);
    const float* pBU = ip + (rowU  << 8) + (cc << 2);
    const float* pBD = ip + (rowD  << 8) + (cc << 2);
    const float* pOU = ip + (rowOU << 8) + (cc << 2);
    const float* pOD = ip + (rowOD << 8) + (cc << 2);
    float* pO0 = op + (h << 8) + (cc << 2);

#define LD(p, pl) (*reinterpret_cast<const float4*>((p) + ((pl) << 16)))

    const int Sm1 = S >= 1 ? S - 1 : 0;
    const int Sm2 = S >= 2 ? S - 2 : 0;

    // ---- prologue loads ----
    float4 c0_m2 = LD(pC0, Sm2), c0_m1 = LD(pC0, Sm1);
    float4 c0_t  = LD(pC0, S), c0_t1 = LD(pC0, S + 1), c0_t2 = LD(pC0, S + 2);
    float4 c1_m2 = LD(pC1, Sm2), c1_m1 = LD(pC1, Sm1);
    float4 c1_t  = LD(pC1, S), c1_t1 = LD(pC1, S + 1), c1_t2 = LD(pC1, S + 2);
    float4 bu_m = LD(pBU, Sm1), bu_c = LD(pBU, S), bu_p = LD(pBU, S + 1);
    float4 bd_m = LD(pBD, Sm1), bd_c = LD(pBD, S), bd_p = LD(pBD, S + 1);
    float4 ou = LD(pOU, S), od = LD(pOD, S);

    // i*_m = iter1(S-1, row) — garbage at S==0, never used (guarded by fm)
    float4 i0_m = i1core(c0_m1);
    i0_m = f4mul(i0_m, c0_t);
    if (S >= 2) i0_m = f4mul(i0_m, c0_m2);
    if (vbU)    i0_m = f4mul(i0_m, bu_m);
    i0_m = f4mul(i0_m, c1_m1);

    float4 i1_m = i1core(c1_m1);
    i1_m = f4mul(i1_m, c1_t);
    if (S >= 2) i1_m = f4mul(i1_m, c1_m2);
    i1_m = f4mul(i1_m, c0_m1);
    if (vbD)    i1_m = f4mul(i1_m, bd_m);

    // i*_c = iter1(S, row)
    float4 i0_c = i1core(c0_t);
    if (S >= 1) i0_c = f4mul(i0_c, c0_m1);
    i0_c = f4mul(i0_c, c0_t1);
    if (vbU)    i0_c = f4mul(i0_c, bu_c);
    i0_c = f4mul(i0_c, c1_t);

    float4 i1_c = i1core(c1_t);
    if (S >= 1) i1_c = f4mul(i1_c, c1_m1);
    i1_c = f4mul(i1_c, c1_t1);
    i1_c = f4mul(i1_c, c0_t);
    if (vbD)    i1_c = f4mul(i1_c, bd_c);

    for (int t = S; t < S + DT; ++t) {
        const int tp3 = t + 3 <= DD - 1 ? t + 3 : DD - 1;
        const int tp2 = t + 2 <= DD - 1 ? t + 2 : DD - 1;
        const int tp1 = t + 1 <= DD - 1 ? t + 1 : DD - 1;

        // ---- prefetch for next step ----
        float4 pf_c0 = LD(pC0, tp3), pf_c1 = LD(pC1, tp3);
        float4 pf_bu = LD(pBU, tp2), pf_bd = LD(pBD, tp2);
        float4 pf_ou = LD(pOU, tp1), pf_od = LD(pOD, tp1);

        const bool fm  = (t > 0);
        const bool fp  = (t < DD - 1);
        const bool fD2 = (t < DD - 2);

        // ---- boundary-row iter1 at plane t ----
        float4 IbU = {1.f, 1.f, 1.f, 1.f};
        if (vbU) {
            IbU = i1core(bu_c);
            if (fm)  IbU = f4mul(IbU, bu_m);
            if (fp)  IbU = f4mul(IbU, bu_p);
            if (voU) IbU = f4mul(IbU, ou);
            IbU = f4mul(IbU, c0_t);
        }
        float4 IbD = {1.f, 1.f, 1.f, 1.f};
        if (vbD) {
            IbD = i1core(bd_c);
            if (fm)  IbD = f4mul(IbD, bd_m);
            if (fp)  IbD = f4mul(IbD, bd_p);
            IbD = f4mul(IbD, c1_t);
            if (voD) IbD = f4mul(IbD, od);
        }

        // ---- iter1(t+1, own rows) ----
        float4 i0_p = i1core(c0_t1);
        i0_p = f4mul(i0_p, c0_t);
        if (fD2) i0_p = f4mul(i0_p, c0_t2);
        if (vbU) i0_p = f4mul(i0_p, bu_p);
        i0_p = f4mul(i0_p, c1_t1);

        float4 i1_p = i1core(c1_t1);
        i1_p = f4mul(i1_p, c1_t);
        if (fD2) i1_p = f4mul(i1_p, c1_t2);
        i1_p = f4mul(i1_p, c0_t1);
        if (vbD) i1_p = f4mul(i1_p, bd_p);

        // ---- iter2 outputs at plane t ----
        float4 o0 = i1core(i0_c);
        if (fm) o0 = f4mul(o0, i0_m);
        if (fp) o0 = f4mul(o0, i0_p);
        o0 = f4mul(o0, IbU);
        o0 = f4mul(o0, i1_c);       // row h+1's iter1 — in-register H-neighbor

        float4 o1 = i1core(i1_c);
        if (fm) o1 = f4mul(o1, i1_m);
        if (fp) o1 = f4mul(o1, i1_p);
        o1 = f4mul(o1, i0_c);
        o1 = f4mul(o1, IbD);

        nfloat4 v0 = {o0.x, o0.y, o0.z, o0.w};
        nfloat4 v1 = {o1.x, o1.y, o1.z, o1.w};
        __builtin_nontemporal_store(v0, reinterpret_cast<nfloat4*>(pO0 + (t << 16)));
        __builtin_nontemporal_store(v1, reinterpret_cast<nfloat4*>(pO0 + (t << 16) + 256));

        // ---- roll ----
        i0_m = i0_c; i0_c = i0_p; i1_m = i1_c; i1_c = i1_p;
        c0_t = c0_t1; c0_t1 = c0_t2; c0_t2 = pf_c0;
        c1_t = c1_t1; c1_t1 = c1_t2; c1_t2 = pf_c1;
        bu_m = bu_c; bu_c = bu_p; bu_p = pf_bu;
        bd_m = bd_c; bd_c = bd_p; bd_p = pf_bd;
        ou = pf_ou; od = pf_od;
    }
#undef LD
}

extern "C" void kernel_launch(void* const* d_in, const int* in_sizes, int n_in,
                              void* d_out, int out_size, void* d_ws, size_t ws_size,
                              hipStream_t stream) {
    const float* in  = (const float*)d_in[0];
    float*       out = (float*)d_out;

    // 32 H-blocks (8 rows) * 32 D-chunks (8 planes) * 2 batch = 2048 blocks
    dim3 block(256);
    dim3 grid(2048);
    erode6_fused<<<grid, block, 0, stream>>>(in, out);
}

// Round 7
// 46.833 us; speedup vs baseline: 4.1476x; 1.0079x over previous
//
#include <hip/hip_runtime.h>

// SoftErosion3D, connectivity=6, iterations=2, [2,1,256,256,256] f32.
//   iter1(x) = x^2 * prod(6 face nbrs), pad 1.0 ; out = iter1(iter1(im))
// Fused, no LDS, no barriers. Wave = full W row (64 lanes x float4); w+-1 via
// intra-wave shuffles. Thread owns rows h,h+1; boundary predicates in SGPR.
// R6: 2-deep load prefetch (loads at step t first consumed at t+2) + unroll.

#define DD 256
#define HH 256
#define HW 65536
#define DT 8

typedef float nfloat4 __attribute__((ext_vector_type(4)));

__device__ __forceinline__ float wleft(float x) {     // lane-1's x ; lane0 -> 1.0
    float v = __shfl_up(x, 1, 64);
    return ((threadIdx.x & 63) == 0) ? 1.0f : v;
}
__device__ __forceinline__ float wright(float x) {    // lane+1's x ; lane63 -> 1.0
    float v = __shfl_down(x, 1, 64);
    return ((threadIdx.x & 63) == 63) ? 1.0f : v;
}
__device__ __forceinline__ float4 f4mul(float4 a, float4 b) {
    a.x *= b.x; a.y *= b.y; a.z *= b.z; a.w *= b.w; return a;
}
__device__ __forceinline__ float4 i1core(float4 c) {  // c^2 * W-neighbors
    float lw = wleft(c.w), rw = wright(c.x);
    float4 r;
    r.x = c.x * c.x * (lw  * c.y);
    r.y = c.y * c.y * (c.x * c.z);
    r.z = c.z * c.z * (c.y * c.w);
    r.w = c.w * c.w * (c.z * rw);
    return r;
}
__device__ __forceinline__ int dcl(int d) { return d < 0 ? 0 : (d > DD - 1 ? DD - 1 : d); }

__global__ __launch_bounds__(256) void erode6_fused(const float* __restrict__ in,
                                                    float* __restrict__ out) {
    const int bx  = blockIdx.x;
    const int swz = (bx & 7) * 256 + (bx >> 3);   // bijective XCD chunking (2048%8==0)

    const int cc = threadIdx.x & 63;              // f4 column, w = cc*4
    const int wv = __builtin_amdgcn_readfirstlane((int)(threadIdx.x >> 6));

    const int hblk = swz & 31;          // 32 H-blocks of 8 rows
    const int dchk = (swz >> 5) & 31;   // 32 D-chunks of 8 planes
    const int b    = swz >> 10;         // batch

    const int h = hblk * 8 + wv * 2;    // own rows h, h+1
    const int S = dchk * DT;

    const bool vbU = (h >= 1);
    const bool voU = (h >= 2);
    const bool vbD = (h + 2 <= HH - 1);
    const bool voD = (h + 3 <= HH - 1);
    const int rowU  = vbU ? h - 1 : 0;
    const int rowOU = voU ? h - 2 : 0;
    const int rowD  = vbD ? h + 2 : HH - 1;
    const int rowOD = voD ? h + 3 : HH - 1;

    const float* __restrict__ ip = in  + (size_t)b * (DD * HW);
    float* __restrict__       op = out + (size_t)b * (DD * HW);

    const float* pC0 = ip + (h     << 8) + (cc << 2);
    const float* pC1 = ip + ((h+1) << 8) + (cc << 2);
    const float* pBU = ip + (rowU  << 8) + (cc << 2);
    const float* pBD = ip + (rowD  << 8) + (cc << 2);
    const float* pOU = ip + (rowOU << 8) + (cc << 2);
    const float* pOD = ip + (rowOD << 8) + (cc << 2);
    float* pO0 = op + (h << 8) + (cc << 2);

#define LD(p, pl) (*reinterpret_cast<const float4*>((p) + ((pl) << 16)))

    const int Sm1 = S >= 1 ? S - 1 : 0;
    const int Sm2 = S >= 2 ? S - 2 : 0;

    // ---- prologue loads ----
    float4 c0_m2 = LD(pC0, Sm2), c0_m1 = LD(pC0, Sm1);
    float4 c0_t  = LD(pC0, S), c0_t1 = LD(pC0, S + 1), c0_t2 = LD(pC0, S + 2);
    float4 c0_f3 = LD(pC0, dcl(S + 3));
    float4 c1_m2 = LD(pC1, Sm2), c1_m1 = LD(pC1, Sm1);
    float4 c1_t  = LD(pC1, S), c1_t1 = LD(pC1, S + 1), c1_t2 = LD(pC1, S + 2);
    float4 c1_f3 = LD(pC1, dcl(S + 3));
    float4 bu_m = LD(pBU, Sm1), bu_c = LD(pBU, S), bu_p = LD(pBU, S + 1);
    float4 bu_f2 = LD(pBU, dcl(S + 2));
    float4 bd_m = LD(pBD, Sm1), bd_c = LD(pBD, S), bd_p = LD(pBD, S + 1);
    float4 bd_f2 = LD(pBD, dcl(S + 2));
    float4 ou = LD(pOU, S), ou_f1 = LD(pOU, dcl(S + 1));
    float4 od = LD(pOD, S), od_f1 = LD(pOD, dcl(S + 1));

    // i*_m = iter1(S-1, row) — garbage at S==0, never used (guarded by fm)
    float4 i0_m = i1core(c0_m1);
    i0_m = f4mul(i0_m, c0_t);
    if (S >= 2) i0_m = f4mul(i0_m, c0_m2);
    if (vbU)    i0_m = f4mul(i0_m, bu_m);
    i0_m = f4mul(i0_m, c1_m1);

    float4 i1_m = i1core(c1_m1);
    i1_m = f4mul(i1_m, c1_t);
    if (S >= 2) i1_m = f4mul(i1_m, c1_m2);
    i1_m = f4mul(i1_m, c0_m1);
    if (vbD)    i1_m = f4mul(i1_m, bd_m);

    // i*_c = iter1(S, row)
    float4 i0_c = i1core(c0_t);
    if (S >= 1) i0_c = f4mul(i0_c, c0_m1);
    i0_c = f4mul(i0_c, c0_t1);
    if (vbU)    i0_c = f4mul(i0_c, bu_c);
    i0_c = f4mul(i0_c, c1_t);

    float4 i1_c = i1core(c1_t);
    if (S >= 1) i1_c = f4mul(i1_c, c1_m1);
    i1_c = f4mul(i1_c, c1_t1);
    i1_c = f4mul(i1_c, c0_t);
    if (vbD)    i1_c = f4mul(i1_c, bd_c);

#pragma unroll
    for (int k = 0; k < DT; ++k) {
        const int t = S + k;

        // ---- issue 2-deep prefetch (first consumed at step t+2) ----
        float4 pf_c0 = LD(pC0, dcl(t + 4)), pf_c1 = LD(pC1, dcl(t + 4));
        float4 pf_bu = LD(pBU, dcl(t + 3)), pf_bd = LD(pBD, dcl(t + 3));
        float4 pf_ou = LD(pOU, dcl(t + 2)), pf_od = LD(pOD, dcl(t + 2));

        const bool fm  = (t > 0);
        const bool fp  = (t < DD - 1);
        const bool fD2 = (t < DD - 2);

        // ---- boundary-row iter1 at plane t ----
        float4 IbU = {1.f, 1.f, 1.f, 1.f};
        if (vbU) {
            IbU = i1core(bu_c);
            if (fm)  IbU = f4mul(IbU, bu_m);
            if (fp)  IbU = f4mul(IbU, bu_p);
            if (voU) IbU = f4mul(IbU, ou);
            IbU = f4mul(IbU, c0_t);
        }
        float4 IbD = {1.f, 1.f, 1.f, 1.f};
        if (vbD) {
            IbD = i1core(bd_c);
            if (fm)  IbD = f4mul(IbD, bd_m);
            if (fp)  IbD = f4mul(IbD, bd_p);
            IbD = f4mul(IbD, c1_t);
            if (voD) IbD = f4mul(IbD, od);
        }

        // ---- iter1(t+1, own rows) ----
        float4 i0_p = i1core(c0_t1);
        i0_p = f4mul(i0_p, c0_t);
        if (fD2) i0_p = f4mul(i0_p, c0_t2);
        if (vbU) i0_p = f4mul(i0_p, bu_p);
        i0_p = f4mul(i0_p, c1_t1);

        float4 i1_p = i1core(c1_t1);
        i1_p = f4mul(i1_p, c1_t);
        if (fD2) i1_p = f4mul(i1_p, c1_t2);
        i1_p = f4mul(i1_p, c0_t1);
        if (vbD) i1_p = f4mul(i1_p, bd_p);

        // ---- iter2 outputs at plane t ----
        float4 o0 = i1core(i0_c);
        if (fm) o0 = f4mul(o0, i0_m);
        if (fp) o0 = f4mul(o0, i0_p);
        o0 = f4mul(o0, IbU);
        o0 = f4mul(o0, i1_c);       // row h+1's iter1 — in-register H-neighbor

        float4 o1 = i1core(i1_c);
        if (fm) o1 = f4mul(o1, i1_m);
        if (fp) o1 = f4mul(o1, i1_p);
        o1 = f4mul(o1, i0_c);
        o1 = f4mul(o1, IbD);

        nfloat4 v0 = {o0.x, o0.y, o0.z, o0.w};
        nfloat4 v1 = {o1.x, o1.y, o1.z, o1.w};
        __builtin_nontemporal_store(v0, reinterpret_cast<nfloat4*>(pO0 + (t << 16)));
        __builtin_nontemporal_store(v1, reinterpret_cast<nfloat4*>(pO0 + (t << 16) + 256));

        // ---- roll (one extra pipeline stage vs R5) ----
        i0_m = i0_c; i0_c = i0_p; i1_m = i1_c; i1_c = i1_p;
        c0_t = c0_t1; c0_t1 = c0_t2; c0_t2 = c0_f3; c0_f3 = pf_c0;
        c1_t = c1_t1; c1_t1 = c1_t2; c1_t2 = c1_f3; c1_f3 = pf_c1;
        bu_m = bu_c; bu_c = bu_p; bu_p = bu_f2; bu_f2 = pf_bu;
        bd_m = bd_c; bd_c = bd_p; bd_p = bd_f2; bd_f2 = pf_bd;
        ou = ou_f1; ou_f1 = pf_ou;
        od = od_f1; od_f1 = pf_od;
    }
#undef LD
}

extern "C" void kernel_launch(void* const* d_in, const int* in_sizes, int n_in,
                              void* d_out, int out_size, void* d_ws, size_t ws_size,
                              hipStream_t stream) {
    const float* in  = (const float*)d_in[0];
    float*       out = (float*)d_out;

    // 32 H-blocks (8 rows) * 32 D-chunks (8 planes) * 2 batch = 2048 blocks
    dim3 block(256);
    dim3 grid(2048);
    erode6_fused<<<grid, block, 0, stream>>>(in, out);
}